// Round 4
// baseline (1902.524 us; speedup 1.0000x reference)
//
#include <hip/hip_runtime.h>
#include <math.h>

#define NN 100000
#define NPAD 100096
#define NT 782        // NPAD / 128
#define NE 800000
#define DD 128

typedef __attribute__((ext_vector_type(8))) short short8;
typedef __attribute__((ext_vector_type(4))) float floatx4;
typedef unsigned int uint_t;

__device__ __forceinline__ unsigned short f2bf(float f) {
    unsigned u = __float_as_uint(f);
    return (unsigned short)((u + 0x7fffu + ((u >> 16) & 1u)) >> 16);
}
__device__ __forceinline__ uint_t pack_split(float f) {
    unsigned short h = f2bf(f);
    float hf = __uint_as_float((unsigned)h << 16);
    unsigned short l = f2bf(f - hf);
    return ((uint_t)h << 16) | (uint_t)l;
}
__device__ __forceinline__ float unpack_sum(uint_t p) {
    return __uint_as_float(p & 0xffff0000u) + __uint_as_float(p << 16);
}
// fragment-order address of element (n, k) in an activation matrix
__device__ __forceinline__ int fragidx(int n, int k) {
    return ((n >> 7) << 14) + ((k >> 5) << 12) + (((n >> 4) & 7) << 9)
         + (((k >> 3) & 3) << 7) + ((n & 15) << 3) + (k & 7);
}
// build short8 of hi (sel=0x07060302) or lo (sel=0x05040100) halves from 8 packed uints
__device__ __forceinline__ short8 permpack(uint4 a, uint4 b, uint_t sel) {
    union { uint_t u[4]; short8 s; } r;
    r.u[0] = __builtin_amdgcn_perm(a.y, a.x, sel);
    r.u[1] = __builtin_amdgcn_perm(a.w, a.z, sel);
    r.u[2] = __builtin_amdgcn_perm(b.y, b.x, sel);
    r.u[3] = __builtin_amdgcn_perm(b.w, b.z, sel);
    return r.s;
}

// ---------------------------------------------------------------- row means of edge-type table
__global__ void rowmean_kernel(const float* __restrict__ tab, float* __restrict__ rm) {
    int r = blockIdx.x;
    int t = threadIdx.x;
    float v = tab[r * DD + t];
    #pragma unroll
    for (int o = 32; o > 0; o >>= 1) v += __shfl_xor(v, o);
    __shared__ float red[2];
    if ((t & 63) == 0) red[t >> 6] = v;
    __syncthreads();
    if (t == 0) rm[r] = (red[0] + red[1]) * (1.0f / DD);
}

// ---------------------------------------------------------------- CSR build
__global__ void hist_kernel(const int* __restrict__ dst, int* __restrict__ fill) {
    int e = blockIdx.x * 256 + threadIdx.x;
    if (e < NE) atomicAdd(&fill[dst[e]], 1);
}

__global__ __launch_bounds__(1024) void scan_kernel(const int* __restrict__ cnt,
                                                    int* __restrict__ rp) {
    __shared__ int wsum[16];
    __shared__ int carry_s;
    int t = threadIdx.x;
    int lane = t & 63, w = t >> 6;
    if (t == 0) { carry_s = 0; rp[0] = 0; }
    __syncthreads();
    for (int base = 0; base < NN; base += 1024) {
        int i = base + t;
        int v = (i < NN) ? cnt[i] : 0;
        int sv = v;
        #pragma unroll
        for (int off = 1; off < 64; off <<= 1) {
            int u = __shfl_up(sv, off);
            if (lane >= off) sv += u;
        }
        if (lane == 63) wsum[w] = sv;
        __syncthreads();
        int woff = carry_s;
        for (int j = 0; j < w; ++j) woff += wsum[j];
        if (i < NN) rp[i + 1] = sv + woff;
        __syncthreads();
        if (t == 0) {
            int tot = 0;
            for (int j = 0; j < 16; ++j) tot += wsum[j];
            carry_s += tot;
        }
        __syncthreads();
    }
}

__global__ void place_kernel(const int* __restrict__ src, const int* __restrict__ dst,
                             const int* __restrict__ et, const float* __restrict__ rm,
                             const int* __restrict__ rp, int* __restrict__ fill,
                             int* __restrict__ csr_s, float* __restrict__ csr_w) {
    int e = blockIdx.x * 256 + threadIdx.x;
    if (e < NE) {
        int d = dst[e];
        int pos = rp[d] + atomicAdd(&fill[d], 1);
        csr_s[pos] = src[e];
        csr_w[pos] = rm[et[e] - 1];
    }
}

// ---------------------------------------------------------------- embedding gather → frag-packed
__global__ void embed_kernel(const int* __restrict__ ids, const float* __restrict__ tab,
                             uint_t* __restrict__ xp) {
    int tid = blockIdx.x * 256 + threadIdx.x;   // NPAD*16
    int n = tid >> 4, c = tid & 15;
    if (n >= NPAD) return;
    int base = fragidx(n, c * 8);
    if (n < NN) {
        const float4* srcp = (const float4*)(tab + (size_t)(ids[n] + 1) * DD + c * 8);
        float4 v0 = srcp[0], v1 = srcp[1];
        uint4 o0, o1;
        o0.x = pack_split(v0.x); o0.y = pack_split(v0.y);
        o0.z = pack_split(v0.z); o0.w = pack_split(v0.w);
        o1.x = pack_split(v1.x); o1.y = pack_split(v1.y);
        o1.z = pack_split(v1.z); o1.w = pack_split(v1.w);
        *(uint4*)(xp + base) = o0;
        *(uint4*)(xp + base + 4) = o1;
    } else {
        uint4 z = make_uint4(0, 0, 0, 0);
        *(uint4*)(xp + base) = z;
        *(uint4*)(xp + base + 4) = z;
    }
}

// ---------------------------------------------------------------- weight prep (unchanged layout)
// mats 0..2: Whh gates r,z,n | 3..5: Wih gates r,z,n | 6..9: ggnn layer W
__global__ void wprep_kernel(const float* __restrict__ Wih, const float* __restrict__ Whh,
                             const float* __restrict__ G, unsigned short* __restrict__ WB) {
    int idx = blockIdx.x * 256 + threadIdx.x;   // 10*16384
    int mat = idx >> 14;
    int rem = idx & 16383;
    int col = rem & 127, kk = rem >> 7;
    float w;
    if (mat < 3)      w = Whh[((size_t)mat * 128 + col) * 128 + kk];
    else if (mat < 6) w = Wih[((size_t)(mat - 3) * 128 + col) * 128 + kk];
    else              w = G[(size_t)(mat - 6) * 16384 + (size_t)kk * 128 + col];
    int chunk = kk >> 5, klo = kk & 31;
    int inoff = ((col >> 4) * 4 + (klo >> 3)) * 128 + (col & 15) * 8 + (klo & 7);
    unsigned short h = f2bf(w);
    float hf = __uint_as_float((unsigned)h << 16);
    unsigned short l = f2bf(w - hf);
    size_t base = (size_t)((mat * 4 + chunk) * 2) * 4096;
    WB[base + inoff] = h;
    WB[base + 4096 + inoff] = l;
}

// ---------------------------------------------------------------- m = x @ W  (no LDS, no barriers)
__global__ __launch_bounds__(512, 3) void gemm_mfma_kernel(const uint_t* __restrict__ xPK,
                                                           const unsigned short* __restrict__ WB,
                                                           int mat, uint_t* __restrict__ mPK) {
    int t = threadIdx.x;
    int tb = blockIdx.x;
    int l = t & 63, w = t >> 6;
    int rowgrp = w >> 2, colgrp = w & 3;
    int lg = l >> 4, lc = l & 15;
    floatx4 acc[4][2];
    #pragma unroll
    for (int i = 0; i < 4; ++i)
        #pragma unroll
        for (int j = 0; j < 2; ++j) acc[i][j] = (floatx4)0.f;
    const uint_t* xT = xPK + (size_t)tb * 16384;
    #pragma unroll
    for (int kc = 0; kc < 4; ++kc) {
        short8 aH[4], aL[4];
        #pragma unroll
        for (int i = 0; i < 4; ++i) {
            int off = kc * 4096 + (rowgrp * 4 + i) * 512 + lg * 128 + lc * 8;
            uint4 p0 = *(const uint4*)(xT + off);
            uint4 p1 = *(const uint4*)(xT + off + 4);
            aH[i] = permpack(p0, p1, 0x07060302u);
            aL[i] = permpack(p0, p1, 0x05040100u);
        }
        #pragma unroll
        for (int j = 0; j < 2; ++j) {
            int boff = (((colgrp * 2 + j) * 4 + lg) * 16 + lc) * 8;
            const unsigned short* wb = WB + (size_t)((mat * 4 + kc) * 2) * 4096;
            short8 bH = *(const short8*)(wb + boff);
            short8 bL = *(const short8*)(wb + 4096 + boff);
            #pragma unroll
            for (int i = 0; i < 4; ++i) {
                acc[i][j] = __builtin_amdgcn_mfma_f32_16x16x32_bf16(aH[i], bH, acc[i][j], 0, 0, 0);
                acc[i][j] = __builtin_amdgcn_mfma_f32_16x16x32_bf16(aH[i], bL, acc[i][j], 0, 0, 0);
                acc[i][j] = __builtin_amdgcn_mfma_f32_16x16x32_bf16(aL[i], bH, acc[i][j], 0, 0, 0);
            }
        }
    }
    #pragma unroll
    for (int j = 0; j < 2; ++j)
        #pragma unroll
        for (int i = 0; i < 4; ++i)
            #pragma unroll
            for (int r = 0; r < 4; ++r) {
                int idx = tb * 16384 + colgrp * 4096 + (rowgrp * 4 + i) * 512
                        + (j * 2 + (lc >> 3)) * 128 + (lg * 4 + r) * 8 + (lc & 7);
                mPK[idx] = pack_split(acc[i][j][r]);   // pad rows deterministic (x pad = 0)
            }
}

// ---------------------------------------------------------------- CSR aggregation (frag-packed)
__global__ __launch_bounds__(256) void agg_kernel(const uint_t* __restrict__ m,
                                                  const int* __restrict__ rp,
                                                  const int* __restrict__ csr_s,
                                                  const float* __restrict__ csr_w,
                                                  uint_t* __restrict__ aggp) {
    int t = threadIdx.x;
    int grp = t >> 5, c = t & 31;
    int n = blockIdx.x * 8 + grp;
    if (n >= NPAD) return;
    int coff = (c >> 3) * 4096 + ((c >> 1) & 3) * 128 + (c & 1) * 4;
    int nout = (n >> 7) * 16384 + ((n >> 4) & 7) * 512 + (n & 15) * 8 + coff;
    if (n >= NN) {
        *(uint4*)(aggp + nout) = make_uint4(0, 0, 0, 0);
        return;
    }
    int e0 = rp[n], e1 = rp[n + 1];
    float4 acc = make_float4(0.f, 0.f, 0.f, 0.f);
    for (int e = e0; e < e1; ++e) {
        float w0 = csr_w[e];
        int s0 = csr_s[e];
        uint4 p = *(const uint4*)(m + (s0 >> 7) * 16384 + ((s0 >> 4) & 7) * 512
                                    + (s0 & 15) * 8 + coff);
        acc.x += w0 * unpack_sum(p.x);
        acc.y += w0 * unpack_sum(p.y);
        acc.z += w0 * unpack_sum(p.z);
        acc.w += w0 * unpack_sum(p.w);
    }
    uint4 o;
    o.x = pack_split(acc.x); o.y = pack_split(acc.y);
    o.z = pack_split(acc.z); o.w = pack_split(acc.w);
    *(uint4*)(aggp + nout) = o;
}

// ---------------------------------------------------------------- fused GRU (no LDS, no barriers)
// pass 0: A = x   vs Whh (mats 0..2) → accR,accZ,accN ; pass 1: A = agg vs Wih (3..5) → accR,accZ,accI
__global__ __launch_bounds__(512, 2) void gru_mfma_kernel(const uint_t* __restrict__ aggPK,
                                                          const uint_t* __restrict__ xPK,
                                                          const unsigned short* __restrict__ WB,
                                                          const float* __restrict__ bih,
                                                          const float* __restrict__ bhh,
                                                          uint_t* __restrict__ xo) {
    int t = threadIdx.x;
    int tb = blockIdx.x;
    int l = t & 63, w = t >> 6;
    int rowgrp = w >> 2, colgrp = w & 3;
    int lg = l >> 4, lc = l & 15;
    floatx4 accR[4][2], accZ[4][2], accN[4][2], accI[4][2];
    #pragma unroll
    for (int i = 0; i < 4; ++i)
        #pragma unroll
        for (int j = 0; j < 2; ++j) {
            accR[i][j] = (floatx4)0.f; accZ[i][j] = (floatx4)0.f;
            accN[i][j] = (floatx4)0.f; accI[i][j] = (floatx4)0.f;
        }
    #pragma unroll
    for (int pass = 0; pass < 2; ++pass) {
        const uint_t* Ap = (pass ? aggPK : xPK) + (size_t)tb * 16384;
        int matbase = pass ? 3 : 0;
        #pragma unroll
        for (int kc = 0; kc < 4; ++kc) {
            short8 aH[4], aL[4];
            #pragma unroll
            for (int i = 0; i < 4; ++i) {
                int off = kc * 4096 + (rowgrp * 4 + i) * 512 + lg * 128 + lc * 8;
                uint4 p0 = *(const uint4*)(Ap + off);
                uint4 p1 = *(const uint4*)(Ap + off + 4);
                aH[i] = permpack(p0, p1, 0x07060302u);
                aL[i] = permpack(p0, p1, 0x05040100u);
            }
            #pragma unroll
            for (int m3 = 0; m3 < 3; ++m3) {
                floatx4 (*accp)[2] = (m3 == 0) ? accR : (m3 == 1) ? accZ : (pass ? accI : accN);
                const unsigned short* wb =
                    WB + (size_t)(((matbase + m3) * 4 + kc) * 2) * 4096;
                #pragma unroll
                for (int j = 0; j < 2; ++j) {
                    int boff = (((colgrp * 2 + j) * 4 + lg) * 16 + lc) * 8;
                    short8 bH = *(const short8*)(wb + boff);
                    short8 bL = *(const short8*)(wb + 4096 + boff);
                    #pragma unroll
                    for (int i = 0; i < 4; ++i) {
                        accp[i][j] = __builtin_amdgcn_mfma_f32_16x16x32_bf16(aH[i], bH, accp[i][j], 0, 0, 0);
                        accp[i][j] = __builtin_amdgcn_mfma_f32_16x16x32_bf16(aH[i], bL, accp[i][j], 0, 0, 0);
                        accp[i][j] = __builtin_amdgcn_mfma_f32_16x16x32_bf16(aL[i], bH, accp[i][j], 0, 0, 0);
                    }
                }
            }
        }
    }
    // epilogue: gates + blend, read h from xPK, write frag-packed
    #pragma unroll
    for (int j = 0; j < 2; ++j) {
        int col = colgrp * 32 + j * 16 + lc;
        float bIr = bih[col],       bHr = bhh[col];
        float bIz = bih[128 + col], bHz = bhh[128 + col];
        float bIn = bih[256 + col], bHn = bhh[256 + col];
        #pragma unroll
        for (int i = 0; i < 4; ++i)
            #pragma unroll
            for (int r = 0; r < 4; ++r) {
                int row = tb * 128 + (rowgrp * 4 + i) * 16 + lg * 4 + r;
                if (row < NN) {
                    int idx = tb * 16384 + colgrp * 4096 + (rowgrp * 4 + i) * 512
                            + (j * 2 + (lc >> 3)) * 128 + (lg * 4 + r) * 8 + (lc & 7);
                    float rr = 1.0f / (1.0f + expf(-(accR[i][j][r] + bIr + bHr)));
                    float zz = 1.0f / (1.0f + expf(-(accZ[i][j][r] + bIz + bHz)));
                    float nn = tanhf(accI[i][j][r] + bIn + rr * (accN[i][j][r] + bHn));
                    float h = unpack_sum(xPK[idx]);
                    xo[idx] = pack_split((1.0f - zz) * nn + zz * h);
                }
            }
    }
}

// ---------------------------------------------------------------- pooling (frag-packed x)
__global__ void pool1_kernel(const uint_t* __restrict__ xp, const float* __restrict__ gw,
                             const float* __restrict__ gb, float* __restrict__ p) {
    int w = threadIdx.x >> 6, lane = threadIdx.x & 63;
    int n = blockIdx.x * 4 + w;
    float v = unpack_sum(xp[fragidx(n, lane)]) * gw[lane] +
              unpack_sum(xp[fragidx(n, lane + 64)]) * gw[64 + lane];
    #pragma unroll
    for (int o = 32; o > 0; o >>= 1) v += __shfl_xor(v, o);
    if (lane == 0) {
        float s = 1.0f / (1.0f + expf(-(v + gb[0])));
        p[n] = expf(s);
    }
}

__global__ void pool2_kernel(const uint_t* __restrict__ xp, const float* __restrict__ p,
                             float* __restrict__ accum, float* __restrict__ den) {
    int t = threadIdx.x;
    int d = t & 127, g = t >> 7;
    int base = blockIdx.x * 256 + g * 128;
    float acc = 0.f, ps = 0.f;
    for (int j = 0; j < 128; ++j) {
        int n = base + j;
        if (n < NN) {
            float pv = p[n];
            acc += pv * unpack_sum(xp[fragidx(n, d)]);
            ps += pv;
        }
    }
    __shared__ float red[256];
    __shared__ float rps[2];
    red[t] = acc;
    if (d == 0) rps[g] = ps;
    __syncthreads();
    if (g == 0) {
        atomicAdd(&accum[d], acc + red[128 + d]);
        if (t == 0) atomicAdd(den, rps[0] + rps[1]);
    }
}

__global__ void finalize_kernel(const float* __restrict__ accum, const float* __restrict__ den,
                                float* __restrict__ out) {
    out[threadIdx.x] = accum[threadIdx.x] / den[0];
}

// ---------------------------------------------------------------- launch
extern "C" void kernel_launch(void* const* d_in, const int* in_sizes, int n_in,
                              void* d_out, int out_size, void* d_ws, size_t ws_size,
                              hipStream_t stream) {
    const int*   node_ids    = (const int*)d_in[0];
    const int*   edges       = (const int*)d_in[1];
    const int*   edge_types  = (const int*)d_in[2];
    const float* embed_table = (const float*)d_in[3];
    const float* edge_tab    = (const float*)d_in[4];
    const float* ggnn_w      = (const float*)d_in[5];
    const float* Wih         = (const float*)d_in[6];
    const float* Whh         = (const float*)d_in[7];
    const float* bih         = (const float*)d_in[8];
    const float* bhh         = (const float*)d_in[9];
    const float* gate_w      = (const float*)d_in[10];
    const float* gate_b      = (const float*)d_in[11];
    float* out = (float*)d_out;

    char* wsb = (char*)d_ws;
    uint_t* x_pk   = (uint_t*)wsb;                               // NPAD*128
    uint_t* m_pk   = x_pk + (size_t)NPAD * DD;                   // NPAD*128 (also x_next)
    uint_t* agg_pk = m_pk + (size_t)NPAD * DD;                   // NPAD*128
    unsigned short* WB = (unsigned short*)(agg_pk + (size_t)NPAD * DD);  // 10*4*2*4096
    float* csr_w = (float*)(WB + 10 * 4 * 2 * 4096);             // E
    float* p     = csr_w + NE;                                   // N
    float* accum = p + NN;                                       // 128
    float* den   = accum + DD;                                   // 1
    float* rm    = den + 1;                                      // 7(+1)
    int*   rp    = (int*)(rm + 8);                               // N+1
    int*   fill  = rp + NN + 1;                                  // N
    int*   csr_s = fill + NN;                                    // E

    const int* src = edges;
    const int* dst = edges + NE;

    // one-time prep
    rowmean_kernel<<<7, 128, 0, stream>>>(edge_tab, rm);
    hipMemsetAsync(fill, 0, NN * sizeof(int), stream);
    hist_kernel<<<(NE + 255) / 256, 256, 0, stream>>>(dst, fill);
    scan_kernel<<<1, 1024, 0, stream>>>(fill, rp);
    hipMemsetAsync(fill, 0, NN * sizeof(int), stream);
    place_kernel<<<(NE + 255) / 256, 256, 0, stream>>>(src, dst, edge_types, rm, rp, fill,
                                                       csr_s, csr_w);
    embed_kernel<<<NPAD * 16 / 256, 256, 0, stream>>>(node_ids, embed_table, x_pk);
    wprep_kernel<<<640, 256, 0, stream>>>(Wih, Whh, ggnn_w, WB);

    // 4 GGNN layers
    for (int layer = 0; layer < 4; ++layer) {
        gemm_mfma_kernel<<<NT, 512, 0, stream>>>(x_pk, WB, 6 + layer, m_pk);
        agg_kernel<<<(NPAD + 7) / 8, 256, 0, stream>>>(m_pk, rp, csr_s, csr_w, agg_pk);
        gru_mfma_kernel<<<NT, 512, 0, stream>>>(agg_pk, x_pk, WB, bih, bhh, m_pk);
        uint_t* tmp = x_pk; x_pk = m_pk; m_pk = tmp;
    }

    // global attention pooling
    hipMemsetAsync(accum, 0, (DD + 1) * sizeof(float), stream);
    pool1_kernel<<<NN / 4, 256, 0, stream>>>(x_pk, gate_w, gate_b, p);
    pool2_kernel<<<(NN + 255) / 256, 256, 0, stream>>>(x_pk, p, accum, den);
    finalize_kernel<<<1, 128, 0, stream>>>(accum, den, out);
}

// Round 5
// 1301.034 us; speedup vs baseline: 1.4623x; 1.4623x over previous
//
#include <hip/hip_runtime.h>
#include <math.h>

#define NN 100000
#define NPAD 100096
#define NT 782        // NPAD / 128
#define NE 800000
#define DD 128

typedef __attribute__((ext_vector_type(8))) short short8;
typedef __attribute__((ext_vector_type(4))) float floatx4;
typedef unsigned int uint_t;

__device__ __forceinline__ unsigned short f2bf(float f) {
    unsigned u = __float_as_uint(f);
    return (unsigned short)((u + 0x7fffu + ((u >> 16) & 1u)) >> 16);
}
__device__ __forceinline__ uint_t pack_split(float f) {
    unsigned short h = f2bf(f);
    float hf = __uint_as_float((unsigned)h << 16);
    unsigned short l = f2bf(f - hf);
    return ((uint_t)h << 16) | (uint_t)l;
}
__device__ __forceinline__ float unpack_sum(uint_t p) {
    return __uint_as_float(p & 0xffff0000u) + __uint_as_float(p << 16);
}
// build short8 of hi (sel=0x07060302) or lo (sel=0x05040100) halves from 8 packed uints
__device__ __forceinline__ short8 permpack(uint4 a, uint4 b, uint_t sel) {
    union { uint_t u[4]; short8 s; } r;
    r.u[0] = __builtin_amdgcn_perm(a.y, a.x, sel);
    r.u[1] = __builtin_amdgcn_perm(a.w, a.z, sel);
    r.u[2] = __builtin_amdgcn_perm(b.y, b.x, sel);
    r.u[3] = __builtin_amdgcn_perm(b.w, b.z, sel);
    return r.s;
}

// ---------------------------------------------------------------- row means of edge-type table
__global__ void rowmean_kernel(const float* __restrict__ tab, float* __restrict__ rm) {
    int r = blockIdx.x;
    int t = threadIdx.x;
    float v = tab[r * DD + t];
    #pragma unroll
    for (int o = 32; o > 0; o >>= 1) v += __shfl_xor(v, o);
    __shared__ float red[2];
    if ((t & 63) == 0) red[t >> 6] = v;
    __syncthreads();
    if (t == 0) rm[r] = (red[0] + red[1]) * (1.0f / DD);
}

// ---------------------------------------------------------------- CSR build
__global__ void hist_kernel(const int* __restrict__ dst, int* __restrict__ fill) {
    int e = blockIdx.x * 256 + threadIdx.x;
    if (e < NE) atomicAdd(&fill[dst[e]], 1);
}

__global__ __launch_bounds__(1024) void scan_kernel(const int* __restrict__ cnt,
                                                    int* __restrict__ rp) {
    __shared__ int wsum[16];
    __shared__ int carry_s;
    int t = threadIdx.x;
    int lane = t & 63, w = t >> 6;
    if (t == 0) { carry_s = 0; rp[0] = 0; }
    __syncthreads();
    for (int base = 0; base < NN; base += 1024) {
        int i = base + t;
        int v = (i < NN) ? cnt[i] : 0;
        int sv = v;
        #pragma unroll
        for (int off = 1; off < 64; off <<= 1) {
            int u = __shfl_up(sv, off);
            if (lane >= off) sv += u;
        }
        if (lane == 63) wsum[w] = sv;
        __syncthreads();
        int woff = carry_s;
        for (int j = 0; j < w; ++j) woff += wsum[j];
        if (i < NN) rp[i + 1] = sv + woff;
        __syncthreads();
        if (t == 0) {
            int tot = 0;
            for (int j = 0; j < 16; ++j) tot += wsum[j];
            carry_s += tot;
        }
        __syncthreads();
    }
}

__global__ void place_kernel(const int* __restrict__ src, const int* __restrict__ dst,
                             const int* __restrict__ et, const float* __restrict__ rm,
                             const int* __restrict__ rp, int* __restrict__ fill,
                             int* __restrict__ csr_s, float* __restrict__ csr_w) {
    int e = blockIdx.x * 256 + threadIdx.x;
    if (e < NE) {
        int d = dst[e];
        int pos = rp[d] + atomicAdd(&fill[d], 1);
        csr_s[pos] = src[e];
        csr_w[pos] = rm[et[e] - 1];
    }
}

// ---------------------------------------------------------------- embedding gather → frag-packed x
__global__ void embed_kernel(const int* __restrict__ ids, const float* __restrict__ tab,
                             uint_t* __restrict__ xp) {
    int tid = blockIdx.x * 256 + threadIdx.x;   // NPAD*16
    int n = tid >> 4, c = tid & 15;
    if (n >= NPAD) return;
    int k = c * 8;
    int base = ((n >> 7) << 14) + ((k >> 5) << 12) + (((n >> 4) & 7) << 9)
             + (((k >> 3) & 3) << 7) + ((n & 15) << 3);
    if (n < NN) {
        const float4* srcp = (const float4*)(tab + (size_t)(ids[n] + 1) * DD + k);
        float4 v0 = srcp[0], v1 = srcp[1];
        uint4 o0, o1;
        o0.x = pack_split(v0.x); o0.y = pack_split(v0.y);
        o0.z = pack_split(v0.z); o0.w = pack_split(v0.w);
        o1.x = pack_split(v1.x); o1.y = pack_split(v1.y);
        o1.z = pack_split(v1.z); o1.w = pack_split(v1.w);
        *(uint4*)(xp + base) = o0;
        *(uint4*)(xp + base + 4) = o1;
    } else {
        uint4 z = make_uint4(0, 0, 0, 0);
        *(uint4*)(xp + base) = z;
        *(uint4*)(xp + base + 4) = z;
    }
}

// ---------------------------------------------------------------- weight prep
// mats 0..2: Whh gates r,z,n | 3..5: Wih gates r,z,n | 6..9: ggnn layer W
__global__ void wprep_kernel(const float* __restrict__ Wih, const float* __restrict__ Whh,
                             const float* __restrict__ G, unsigned short* __restrict__ WB) {
    int idx = blockIdx.x * 256 + threadIdx.x;   // 10*16384
    int mat = idx >> 14;
    int rem = idx & 16383;
    int col = rem & 127, kk = rem >> 7;
    float w;
    if (mat < 3)      w = Whh[((size_t)mat * 128 + col) * 128 + kk];
    else if (mat < 6) w = Wih[((size_t)(mat - 3) * 128 + col) * 128 + kk];
    else              w = G[(size_t)(mat - 6) * 16384 + (size_t)kk * 128 + col];
    int chunk = kk >> 5, klo = kk & 31;
    int inoff = ((col >> 4) * 4 + (klo >> 3)) * 128 + (col & 15) * 8 + (klo & 7);
    unsigned short h = f2bf(w);
    float hf = __uint_as_float((unsigned)h << 16);
    unsigned short l = f2bf(w - hf);
    size_t base = (size_t)((mat * 4 + chunk) * 2) * 4096;
    WB[base + inoff] = h;
    WB[base + 4096 + inoff] = l;
}

// ---------------------------------------------------------------- m = x @ W  (zero-LDS MFMA)
// reads frag-packed x, writes ROW-MAJOR packed m (for the edge gather)
__global__ __launch_bounds__(512, 3) void gemm_mfma_kernel(const uint_t* __restrict__ xPK,
                                                           const unsigned short* __restrict__ WB,
                                                           int mat, uint_t* __restrict__ mRM) {
    int t = threadIdx.x;
    int tb = blockIdx.x;
    int l = t & 63, w = t >> 6;
    int rowgrp = w >> 2, colgrp = w & 3;
    int lg = l >> 4, lc = l & 15;
    floatx4 acc[4][2];
    #pragma unroll
    for (int i = 0; i < 4; ++i)
        #pragma unroll
        for (int j = 0; j < 2; ++j) acc[i][j] = (floatx4)0.f;
    const uint_t* xT = xPK + (size_t)tb * 16384;
    #pragma unroll
    for (int kc = 0; kc < 4; ++kc) {
        short8 aH[4], aL[4];
        #pragma unroll
        for (int i = 0; i < 4; ++i) {
            int off = kc * 4096 + (rowgrp * 4 + i) * 512 + lg * 128 + lc * 8;
            uint4 p0 = *(const uint4*)(xT + off);
            uint4 p1 = *(const uint4*)(xT + off + 4);
            aH[i] = permpack(p0, p1, 0x07060302u);
            aL[i] = permpack(p0, p1, 0x05040100u);
        }
        #pragma unroll
        for (int j = 0; j < 2; ++j) {
            int boff = (((colgrp * 2 + j) * 4 + lg) * 16 + lc) * 8;
            const unsigned short* wb = WB + (size_t)((mat * 4 + kc) * 2) * 4096;
            short8 bH = *(const short8*)(wb + boff);
            short8 bL = *(const short8*)(wb + 4096 + boff);
            #pragma unroll
            for (int i = 0; i < 4; ++i) {
                acc[i][j] = __builtin_amdgcn_mfma_f32_16x16x32_bf16(aH[i], bH, acc[i][j], 0, 0, 0);
                acc[i][j] = __builtin_amdgcn_mfma_f32_16x16x32_bf16(aH[i], bL, acc[i][j], 0, 0, 0);
                acc[i][j] = __builtin_amdgcn_mfma_f32_16x16x32_bf16(aL[i], bH, acc[i][j], 0, 0, 0);
            }
        }
    }
    // epilogue: row-major packed write (pad rows included; x pad = 0 so m pad = 0)
    #pragma unroll
    for (int j = 0; j < 2; ++j) {
        int col = (colgrp * 2 + j) * 16 + lc;
        #pragma unroll
        for (int i = 0; i < 4; ++i)
            #pragma unroll
            for (int r = 0; r < 4; ++r) {
                int row = tb * 128 + (rowgrp * 4 + i) * 16 + lg * 4 + r;
                mRM[(size_t)row * DD + col] = pack_split(acc[i][j][r]);
            }
    }
}

// ---------------------------------------------------------------- CSR aggregation
// reads ROW-MAJOR m (512 B contiguous per edge), writes frag-packed agg
__global__ __launch_bounds__(256) void agg_kernel(const uint_t* __restrict__ m,
                                                  const int* __restrict__ rp,
                                                  const int* __restrict__ csr_s,
                                                  const float* __restrict__ csr_w,
                                                  uint_t* __restrict__ aggp) {
    int t = threadIdx.x;
    int grp = t >> 5, c = t & 31;
    int n = blockIdx.x * 8 + grp;
    if (n >= NPAD) return;
    int coff = (c >> 3) * 4096 + ((c >> 1) & 3) * 128 + (c & 1) * 4;
    int nout = (n >> 7) * 16384 + ((n >> 4) & 7) * 512 + (n & 15) * 8 + coff;
    if (n >= NN) {
        *(uint4*)(aggp + nout) = make_uint4(0, 0, 0, 0);
        return;
    }
    int e0 = rp[n], e1 = rp[n + 1];
    float4 acc = make_float4(0.f, 0.f, 0.f, 0.f);
    for (int e = e0; e < e1; ++e) {
        float w0 = csr_w[e];
        int s0 = csr_s[e];
        uint4 p = ((const uint4*)(m + (size_t)s0 * DD))[c];
        acc.x += w0 * unpack_sum(p.x);
        acc.y += w0 * unpack_sum(p.y);
        acc.z += w0 * unpack_sum(p.z);
        acc.w += w0 * unpack_sum(p.w);
    }
    uint4 o;
    o.x = pack_split(acc.x); o.y = pack_split(acc.y);
    o.z = pack_split(acc.z); o.w = pack_split(acc.w);
    *(uint4*)(aggp + nout) = o;
}

// ---------------------------------------------------------------- fused GRU (zero-LDS MFMA)
// pass 0: A = x vs Whh (mats 0..2) → accR,accZ,accN ; pass 1: A = agg vs Wih (3..5) → accR,accZ,accI
__global__ __launch_bounds__(512, 2) void gru_mfma_kernel(const uint_t* __restrict__ aggPK,
                                                          const uint_t* __restrict__ xPK,
                                                          const unsigned short* __restrict__ WB,
                                                          const float* __restrict__ bih,
                                                          const float* __restrict__ bhh,
                                                          uint_t* __restrict__ xo) {
    int t = threadIdx.x;
    int tb = blockIdx.x;
    int l = t & 63, w = t >> 6;
    int rowgrp = w >> 2, colgrp = w & 3;
    int lg = l >> 4, lc = l & 15;
    floatx4 accR[4][2], accZ[4][2], accN[4][2], accI[4][2];
    #pragma unroll
    for (int i = 0; i < 4; ++i)
        #pragma unroll
        for (int j = 0; j < 2; ++j) {
            accR[i][j] = (floatx4)0.f; accZ[i][j] = (floatx4)0.f;
            accN[i][j] = (floatx4)0.f; accI[i][j] = (floatx4)0.f;
        }
    #pragma unroll
    for (int pass = 0; pass < 2; ++pass) {
        const uint_t* Ap = (pass ? aggPK : xPK) + (size_t)tb * 16384;
        int matbase = pass ? 3 : 0;
        #pragma unroll
        for (int kc = 0; kc < 4; ++kc) {
            short8 aH[4], aL[4];
            #pragma unroll
            for (int i = 0; i < 4; ++i) {
                int off = kc * 4096 + (rowgrp * 4 + i) * 512 + lg * 128 + lc * 8;
                uint4 p0 = *(const uint4*)(Ap + off);
                uint4 p1 = *(const uint4*)(Ap + off + 4);
                aH[i] = permpack(p0, p1, 0x07060302u);
                aL[i] = permpack(p0, p1, 0x05040100u);
            }
            #pragma unroll
            for (int m3 = 0; m3 < 3; ++m3) {
                floatx4 (*accp)[2] = (m3 == 0) ? accR : (m3 == 1) ? accZ : (pass ? accI : accN);
                const unsigned short* wb =
                    WB + (size_t)(((matbase + m3) * 4 + kc) * 2) * 4096;
                #pragma unroll
                for (int j = 0; j < 2; ++j) {
                    int boff = (((colgrp * 2 + j) * 4 + lg) * 16 + lc) * 8;
                    short8 bH = *(const short8*)(wb + boff);
                    short8 bL = *(const short8*)(wb + 4096 + boff);
                    #pragma unroll
                    for (int i = 0; i < 4; ++i) {
                        accp[i][j] = __builtin_amdgcn_mfma_f32_16x16x32_bf16(aH[i], bH, accp[i][j], 0, 0, 0);
                        accp[i][j] = __builtin_amdgcn_mfma_f32_16x16x32_bf16(aH[i], bL, accp[i][j], 0, 0, 0);
                        accp[i][j] = __builtin_amdgcn_mfma_f32_16x16x32_bf16(aL[i], bH, accp[i][j], 0, 0, 0);
                    }
                }
            }
        }
    }
    // epilogue: gates + blend, read h from xPK, write frag-packed
    #pragma unroll
    for (int j = 0; j < 2; ++j) {
        int col = colgrp * 32 + j * 16 + lc;
        float bIr = bih[col],       bHr = bhh[col];
        float bIz = bih[128 + col], bHz = bhh[128 + col];
        float bIn = bih[256 + col], bHn = bhh[256 + col];
        #pragma unroll
        for (int i = 0; i < 4; ++i)
            #pragma unroll
            for (int r = 0; r < 4; ++r) {
                int row = tb * 128 + (rowgrp * 4 + i) * 16 + lg * 4 + r;
                if (row < NN) {
                    int idx = tb * 16384 + colgrp * 4096 + (rowgrp * 4 + i) * 512
                            + (j * 2 + (lc >> 3)) * 128 + (lg * 4 + r) * 8 + (lc & 7);
                    float rr = 1.0f / (1.0f + expf(-(accR[i][j][r] + bIr + bHr)));
                    float zz = 1.0f / (1.0f + expf(-(accZ[i][j][r] + bIz + bHz)));
                    float nn = tanhf(accI[i][j][r] + bIn + rr * (accN[i][j][r] + bHn));
                    float h = unpack_sum(xPK[idx]);
                    xo[idx] = pack_split((1.0f - zz) * nn + zz * h);
                }
            }
    }
}

// ---------------------------------------------------------------- fused pooling (tile-based)
// one block per 128-row tile; linear coalesced reads of frag-packed x.
// thread t owns cols colb..colb+7 (kc=t>>6, cb=(t>>1)&3) and rows rg*16+rlh*8+{0..7}.
__global__ __launch_bounds__(256) void pool_kernel(const uint_t* __restrict__ xp,
                                                   const float* __restrict__ gw,
                                                   const float* __restrict__ gb,
                                                   float* __restrict__ accum,
                                                   float* __restrict__ den) {
    __shared__ float sgw[128];
    __shared__ float rowsum[128];
    __shared__ float pl[128];
    __shared__ float acc2[128];
    int t = threadIdx.x;
    int tb = blockIdx.x;
    if (t < 128) { sgw[t] = gw[t]; rowsum[t] = 0.f; acc2[t] = 0.f; }
    __syncthreads();
    const uint_t* xt = xp + (size_t)tb * 16384;
    int kc = t >> 6, rg = (t >> 3) & 7, cb = (t >> 1) & 3, rlh = t & 1;
    int colb = kc * 32 + cb * 8;
    uint4 st[16];
    float g0 = sgw[colb], g1 = sgw[colb + 1], g2 = sgw[colb + 2], g3 = sgw[colb + 3];
    float g4 = sgw[colb + 4], g5 = sgw[colb + 5], g6 = sgw[colb + 6], g7 = sgw[colb + 7];
    #pragma unroll
    for (int jh = 0; jh < 8; ++jh) {
        int base = t * 64 + jh * 8;
        uint4 a = *(const uint4*)(xt + base);
        uint4 b = *(const uint4*)(xt + base + 4);
        st[2 * jh] = a; st[2 * jh + 1] = b;
        float s = unpack_sum(a.x) * g0 + unpack_sum(a.y) * g1
                + unpack_sum(a.z) * g2 + unpack_sum(a.w) * g3
                + unpack_sum(b.x) * g4 + unpack_sum(b.y) * g5
                + unpack_sum(b.z) * g6 + unpack_sum(b.w) * g7;
        atomicAdd(&rowsum[rg * 16 + rlh * 8 + jh], s);
    }
    __syncthreads();
    if (t < 128) {
        int row = tb * 128 + t;
        float pv = 0.f;
        if (row < NN) {
            float s = 1.0f / (1.0f + expf(-(rowsum[t] + gb[0])));
            pv = expf(s);                        // s in (0,1): no max-subtract needed
        }
        pl[t] = pv;
    }
    __syncthreads();
    float ws0 = 0.f, ws1 = 0.f, ws2 = 0.f, ws3 = 0.f;
    float ws4 = 0.f, ws5 = 0.f, ws6 = 0.f, ws7 = 0.f;
    #pragma unroll
    for (int jh = 0; jh < 8; ++jh) {
        float pv = pl[rg * 16 + rlh * 8 + jh];
        uint4 a = st[2 * jh], b = st[2 * jh + 1];
        ws0 += pv * unpack_sum(a.x); ws1 += pv * unpack_sum(a.y);
        ws2 += pv * unpack_sum(a.z); ws3 += pv * unpack_sum(a.w);
        ws4 += pv * unpack_sum(b.x); ws5 += pv * unpack_sum(b.y);
        ws6 += pv * unpack_sum(b.z); ws7 += pv * unpack_sum(b.w);
    }
    atomicAdd(&acc2[colb], ws0);     atomicAdd(&acc2[colb + 1], ws1);
    atomicAdd(&acc2[colb + 2], ws2); atomicAdd(&acc2[colb + 3], ws3);
    atomicAdd(&acc2[colb + 4], ws4); atomicAdd(&acc2[colb + 5], ws5);
    atomicAdd(&acc2[colb + 6], ws6); atomicAdd(&acc2[colb + 7], ws7);
    __syncthreads();
    if (t < 128) atomicAdd(&accum[t], acc2[t]);
    if (t < 64) {
        float v = pl[t] + pl[t + 64];
        #pragma unroll
        for (int o = 32; o > 0; o >>= 1) v += __shfl_xor(v, o);
        if (t == 0) atomicAdd(den, v);
    }
}

__global__ void finalize_kernel(const float* __restrict__ accum, const float* __restrict__ den,
                                float* __restrict__ out) {
    out[threadIdx.x] = accum[threadIdx.x] / den[0];
}

// ---------------------------------------------------------------- launch
extern "C" void kernel_launch(void* const* d_in, const int* in_sizes, int n_in,
                              void* d_out, int out_size, void* d_ws, size_t ws_size,
                              hipStream_t stream) {
    const int*   node_ids    = (const int*)d_in[0];
    const int*   edges       = (const int*)d_in[1];
    const int*   edge_types  = (const int*)d_in[2];
    const float* embed_table = (const float*)d_in[3];
    const float* edge_tab    = (const float*)d_in[4];
    const float* ggnn_w      = (const float*)d_in[5];
    const float* Wih         = (const float*)d_in[6];
    const float* Whh         = (const float*)d_in[7];
    const float* bih         = (const float*)d_in[8];
    const float* bhh         = (const float*)d_in[9];
    const float* gate_w      = (const float*)d_in[10];
    const float* gate_b      = (const float*)d_in[11];
    float* out = (float*)d_out;

    char* wsb = (char*)d_ws;
    uint_t* x_pk   = (uint_t*)wsb;                               // NPAD*128 (frag-packed)
    uint_t* x2_pk  = x_pk + (size_t)NPAD * DD;                   // NPAD*128 (frag-packed, x_next)
    uint_t* m_rm   = x2_pk + (size_t)NPAD * DD;                  // NPAD*128 (ROW-MAJOR packed)
    uint_t* agg_pk = m_rm + (size_t)NPAD * DD;                   // NPAD*128 (frag-packed)
    unsigned short* WB = (unsigned short*)(agg_pk + (size_t)NPAD * DD);  // 10*4*2*4096
    float* csr_w = (float*)(WB + 10 * 4 * 2 * 4096);             // E
    float* accum = csr_w + NE;                                   // 128
    float* den   = accum + DD;                                   // 1
    float* rm    = den + 1;                                      // 7(+1)
    int*   rp    = (int*)(rm + 8);                               // N+1
    int*   fill  = rp + NN + 1;                                  // N
    int*   csr_s = fill + NN;                                    // E

    const int* src = edges;
    const int* dst = edges + NE;

    // one-time prep
    rowmean_kernel<<<7, 128, 0, stream>>>(edge_tab, rm);
    hipMemsetAsync(fill, 0, NN * sizeof(int), stream);
    hist_kernel<<<(NE + 255) / 256, 256, 0, stream>>>(dst, fill);
    scan_kernel<<<1, 1024, 0, stream>>>(fill, rp);
    hipMemsetAsync(fill, 0, NN * sizeof(int), stream);
    place_kernel<<<(NE + 255) / 256, 256, 0, stream>>>(src, dst, edge_types, rm, rp, fill,
                                                       csr_s, csr_w);
    embed_kernel<<<NPAD * 16 / 256, 256, 0, stream>>>(node_ids, embed_table, x_pk);
    wprep_kernel<<<640, 256, 0, stream>>>(Wih, Whh, ggnn_w, WB);

    // 4 GGNN layers
    for (int layer = 0; layer < 4; ++layer) {
        gemm_mfma_kernel<<<NT, 512, 0, stream>>>(x_pk, WB, 6 + layer, m_rm);
        agg_kernel<<<(NPAD + 7) / 8, 256, 0, stream>>>(m_rm, rp, csr_s, csr_w, agg_pk);
        gru_mfma_kernel<<<NT, 512, 0, stream>>>(agg_pk, x_pk, WB, bih, bhh, x2_pk);
        uint_t* tmp = x_pk; x_pk = x2_pk; x2_pk = tmp;
    }

    // global attention pooling
    hipMemsetAsync(accum, 0, (DD + 1) * sizeof(float), stream);
    pool_kernel<<<NT, 256, 0, stream>>>(x_pk, gate_w, gate_b, accum, den);
    finalize_kernel<<<1, 128, 0, stream>>>(accum, den, out);
}